// Round 10
// baseline (213.012 us; speedup 1.0000x reference)
//
#include <hip/hip_runtime.h>
#include <hip/hip_bf16.h>

// ---- problem constants ----
#define N_GAUSS 4096
#define N_PTS   32768
#define BLOCK   256
#define NCHUNK  32                  // eval chunks per point-block; grid 32 x 128
#define NBLK_PT 128                 // 128 x 256 = 32768 points
#define GSTRIDE 32                  // floats per packed gaussian = 8 x float4
#define NCELL   4096                // 16^3 morton cells
#define NBIN    16                  // parallel bin blocks (R5-proven shape)
#define RECCAP  128                 // max records per eval chunk (= ceil(4096/32))

#define SH_C0  0.28209479177387814f
#define SH_C1  0.4886025119029199f

// Workspace layout (float index):
#define WS_GP     0                          // 4096*32 = 131072 floats
#define WS_GHIST  131072                     // int[4096]  (scan output / scatter cursor)
#define WS_CELLID 135168                     // int[32768]
#define WS_SPTS   167936                     // float4[32768] (16B aligned)
#define WS_HPART  299008                     // int[16*4096] partial histograms
#define WS_ACT    364544                     // int[128*4096] survivor lists
#define WS_NACT   888832                     // int[128] survivor counts
// total ~888,960 floats = 3.6 MB

__device__ __forceinline__ int cell_of(float x, float y, float z) {
    int cx = min(15, max(0, (int)((x + 3.2f) * 2.5f)));
    int cy = min(15, max(0, (int)((y + 3.2f) * 2.5f)));
    int cz = min(15, max(0, (int)((z + 3.2f) * 2.5f)));
    int ex = (cx & 1) | ((cx & 2) << 2) | ((cx & 4) << 4) | ((cx & 8) << 6);
    int ey = (cy & 1) | ((cy & 2) << 2) | ((cy & 4) << 4) | ((cy & 8) << 6);
    int ez = (cz & 1) | ((cz & 2) << 2) | ((cz & 4) << 4) | ((cz & 8) << 6);
    return ex | (ey << 1) | (ez << 2);
}

// ---------------------------------------------------------------------------
// N1 (28 blocks x 1024): blocks 0..15 bin 2048 pts each (LDS hist -> partial
// dump); blocks 16..19 gaussian prep (float4 record stores); 20..27 zero OUT
// (R10: out is now the atomic accumulation target; 256 KB, half of old acc).
// Record: q0=(cx,cy,cz,Tg) q1=(pxx,pxy,pxz,pyy) q2=(pyz,pzz,lnop,0)
//         q3..q6 = SH (constants pre-multiplied), q7 = pad
// ---------------------------------------------------------------------------
__global__ __launch_bounds__(1024) void binprep_kernel(
    const float* __restrict__ pts, const float* __restrict__ xyz,
    const float* __restrict__ sh_dc, const float* __restrict__ sh_rest,
    const float* __restrict__ scaling, const float* __restrict__ rotation,
    const float* __restrict__ opl, float* __restrict__ gp,
    int* __restrict__ cellid, int* __restrict__ hpart, float* __restrict__ out)
{
    const int t = threadIdx.x, bx = blockIdx.x;

    if (bx >= 20) {
        // zero out[2*N_PTS] = 65536 floats = 16384 float4; 8 blocks x 1024 x 2
        float4* o4 = (float4*)out;
        int base = (bx - 20) * 2048 + t;
        o4[base]        = make_float4(0.f, 0.f, 0.f, 0.f);
        o4[base + 1024] = make_float4(0.f, 0.f, 0.f, 0.f);
        return;
    }
    if (bx >= 16) {
        int g = (bx - 16) * 1024 + t;
        float s0 = scaling[3*g+0], s1 = scaling[3*g+1], s2 = scaling[3*g+2];
        float i0 = __expf(-2.0f * s0);
        float i1 = __expf(-2.0f * s1);
        float i2 = __expf(-2.0f * s2);
        float maxs2 = __expf(2.0f * fmaxf(s0, fmaxf(s1, s2)));

        float r = rotation[4*g+0], x = rotation[4*g+1];
        float y = rotation[4*g+2], z = rotation[4*g+3];
        float n = rsqrtf(r*r + x*x + y*y + z*z);
        r *= n; x *= n; y *= n; z *= n;
        float R00 = 1.f - 2.f*(y*y + z*z), R01 = 2.f*(x*y - r*z), R02 = 2.f*(x*z + r*y);
        float R10 = 2.f*(x*y + r*z), R11 = 1.f - 2.f*(x*x + z*z), R12 = 2.f*(y*z - r*x);
        float R20 = 2.f*(x*z - r*y), R21 = 2.f*(y*z + r*x), R22 = 1.f - 2.f*(x*x + y*y);

        float pxx = 0.5f*(R00*R00*i0 + R01*R01*i1 + R02*R02*i2);
        float pxy = 0.5f*(R00*R10*i0 + R01*R11*i1 + R02*R12*i2);
        float pxz = 0.5f*(R00*R20*i0 + R01*R21*i1 + R02*R22*i2);
        float pyy = 0.5f*(R10*R10*i0 + R11*R11*i1 + R12*R12*i2);
        float pyz = 0.5f*(R10*R20*i0 + R11*R21*i1 + R12*R22*i2);
        float pzz = 0.5f*(R20*R20*i0 + R21*R21*i1 + R22*R22*i2);

        float op   = 1.f / (1.f + __expf(-opl[g]));
        float lnop = __logf(op);
        // d2 > Tg => w < e^-16 ~ 1.1e-7; dropped total ~2e-3 << 4.1e-2 threshold
        float Tg   = 2.0f * maxs2 * (lnop + 16.0f);

        const float* sr = sh_rest + (size_t)g * 15;
        float4* G4 = (float4*)(gp + (size_t)g * GSTRIDE);
        G4[0] = make_float4(xyz[3*g+0], xyz[3*g+1], xyz[3*g+2], Tg);
        G4[1] = make_float4(pxx, pxy, pxz, pyy);
        G4[2] = make_float4(pyz, pzz, lnop, 0.f);
        G4[3] = make_float4( SH_C0 * sh_dc[g],
                            -SH_C1 * sr[0],
                             SH_C1 * sr[1],
                            -SH_C1 * sr[2]);
        G4[4] = make_float4( 1.0925484305920792f  * sr[3],
                            -1.0925484305920792f  * sr[4],
                             0.31539156525252005f * sr[5],
                            -1.0925484305920792f  * sr[6]);
        G4[5] = make_float4( 0.5462742152960396f  * sr[7],
                            -0.5900435899266435f  * sr[8],
                             2.890611442640554f   * sr[9],
                            -0.4570457994644658f  * sr[10]);
        G4[6] = make_float4( 0.3731763325901154f  * sr[11],
                            -0.4570457994644658f  * sr[12],
                             1.445305721320277f   * sr[13],
                            -0.5900435899266435f  * sr[14]);
        G4[7] = make_float4(0.f, 0.f, 0.f, 0.f);
        return;
    }

    // ---- bin blocks 0..15: 2048 points each ----
    __shared__ int s_hist[NCELL];
    #pragma unroll
    for (int i = 0; i < 4; ++i) s_hist[t + i * 1024] = 0;
    __syncthreads();
    #pragma unroll
    for (int k = 0; k < 2; ++k) {
        int p = bx * 2048 + k * 1024 + t;
        float x = pts[3*p+0], y = pts[3*p+1], z = pts[3*p+2];
        int cell = cell_of(x, y, z);
        cellid[p] = cell;
        atomicAdd(&s_hist[cell], 1);
    }
    __syncthreads();
    #pragma unroll
    for (int i = 0; i < 4; ++i) {
        int c = t + i * 1024;
        hpart[bx * NCELL + c] = s_hist[c];
    }
}

// ---------------------------------------------------------------------------
// N2: one block sums 16 partial hists (int4 loads) + exclusive scan -> ghist.
// ---------------------------------------------------------------------------
__global__ __launch_bounds__(1024) void scan_kernel(
    const int* __restrict__ hpart, int* __restrict__ ghist)
{
    __shared__ int s_wsum[16];
    const int t = threadIdx.x;
    const int lane = t & 63, wv = t >> 6;
    const int b = t * 4;

    int4 c = make_int4(0, 0, 0, 0);
    #pragma unroll
    for (int k = 0; k < NBIN; ++k) {
        int4 h = *(const int4*)(hpart + k * NCELL + b);
        c.x += h.x; c.y += h.y; c.z += h.z; c.w += h.w;
    }
    int s = c.x + c.y + c.z + c.w;

    // inclusive scan within wave (64 lanes)
    int incl = s;
    #pragma unroll
    for (int off = 1; off < 64; off <<= 1) {
        int v = __shfl_up(incl, off);
        if (lane >= off) incl += v;
    }
    if (lane == 63) s_wsum[wv] = incl;
    __syncthreads();
    if (wv == 0) {
        int ws = (lane < 16) ? s_wsum[lane] : 0;
        int wincl = ws;
        #pragma unroll
        for (int off = 1; off < 16; off <<= 1) {
            int v = __shfl_up(wincl, off);
            if (lane >= off) wincl += v;
        }
        if (lane < 16) s_wsum[lane] = wincl - ws;   // exclusive wave offset
    }
    __syncthreads();

    int excl = s_wsum[wv] + (incl - s);
    ghist[b]   = excl;
    ghist[b+1] = excl + c.x;
    ghist[b+2] = excl + c.x + c.y;
    ghist[b+3] = excl + c.x + c.y + c.z;
}

// ---------------------------------------------------------------------------
// N3: scatter points into sorted float4 (xyz + bitcast orig index).
// ---------------------------------------------------------------------------
__global__ __launch_bounds__(256) void scatter_kernel(
    const float* __restrict__ pts, const int* __restrict__ cellid,
    int* __restrict__ ghist, float4* __restrict__ spts)
{
    int p = blockIdx.x * 256 + threadIdx.x;
    float x = pts[3*p+0], y = pts[3*p+1], z = pts[3*p+2];
    int pos = atomicAdd(&ghist[cellid[p]], 1);
    spts[pos] = make_float4(x, y, z, __int_as_float(p));
}

// ---------------------------------------------------------------------------
// N4: cull. One block per point-block: AABB once, test all 4096 gaussians,
// emit compacted survivor list + count. (Produced ONCE per pb — R7 lesson:
// never recompute this in the 32x-multiplicity consumer.)
// ---------------------------------------------------------------------------
__global__ __launch_bounds__(BLOCK) void cull_kernel(
    const float4* __restrict__ spts, const float4* __restrict__ gp4,
    int* __restrict__ actlist, int* __restrict__ nactg)
{
    __shared__ float s_min[4][3], s_max[4][3];
    __shared__ int s_n;
    __shared__ int s_list[N_GAUSS];          // 16 KB

    const int tid = threadIdx.x;
    const int pb  = blockIdx.x;
    float4 P = spts[pb * 256 + tid];
    const float px = P.x, py = P.y, pz = P.z;

    // block AABB
    float mnx = px, mxx = px, mny = py, mxy = py, mnz = pz, mxz = pz;
    #pragma unroll
    for (int off = 32; off >= 1; off >>= 1) {
        mnx = fminf(mnx, __shfl_xor(mnx, off));
        mxx = fmaxf(mxx, __shfl_xor(mxx, off));
        mny = fminf(mny, __shfl_xor(mny, off));
        mxy = fmaxf(mxy, __shfl_xor(mxy, off));
        mnz = fminf(mnz, __shfl_xor(mnz, off));
        mxz = fmaxf(mxz, __shfl_xor(mxz, off));
    }
    const int wave = tid >> 6;
    if ((tid & 63) == 0) {
        s_min[wave][0] = mnx; s_min[wave][1] = mny; s_min[wave][2] = mnz;
        s_max[wave][0] = mxx; s_max[wave][1] = mxy; s_max[wave][2] = mxz;
    }
    if (tid == 0) s_n = 0;
    __syncthreads();
    const float bmnx = fminf(fminf(s_min[0][0], s_min[1][0]), fminf(s_min[2][0], s_min[3][0]));
    const float bmny = fminf(fminf(s_min[0][1], s_min[1][1]), fminf(s_min[2][1], s_min[3][1]));
    const float bmnz = fminf(fminf(s_min[0][2], s_min[1][2]), fminf(s_min[2][2], s_min[3][2]));
    const float bmxx = fmaxf(fmaxf(s_max[0][0], s_max[1][0]), fmaxf(s_max[2][0], s_max[3][0]));
    const float bmxy = fmaxf(fmaxf(s_max[0][1], s_max[1][1]), fmaxf(s_max[2][1], s_max[3][1]));
    const float bmxz = fmaxf(fmaxf(s_max[0][2], s_max[1][2]), fmaxf(s_max[2][2], s_max[3][2]));

    for (int r = 0; r < N_GAUSS / BLOCK; ++r) {
        const int gg = r * BLOCK + tid;
        float4 c = gp4[(size_t)gg << 3];
        float ddx = fmaxf(0.f, fmaxf(bmnx - c.x, c.x - bmxx));
        float ddy = fmaxf(0.f, fmaxf(bmny - c.y, c.y - bmxy));
        float ddz = fmaxf(0.f, fmaxf(bmnz - c.z, c.z - bmxz));
        float dd2 = ddx*ddx + ddy*ddy + ddz*ddz;
        if (dd2 <= c.w) {
            int slot = atomicAdd(&s_n, 1);
            s_list[slot] = gg;
        }
    }
    __syncthreads();
    const int n = s_n;
    for (int i = tid; i < n; i += BLOCK) actlist[pb * N_GAUSS + i] = s_list[i];
    if (tid == 0) nactg[pb] = n;
}

// ---------------------------------------------------------------------------
// Eval body for one surviving LDS record (R16-proven math).
// ---------------------------------------------------------------------------
__device__ __forceinline__ void eval_one(
    const float4* R, float dx, float dy, float dz, float d2,
    float& opac, float& sig)
{
    float4 q1 = R[1], q2 = R[2];
    float vx = q1.x*dx + q1.y*dy + q1.z*dz;
    float vy = q1.y*dx + q1.w*dy + q2.x*dz;
    float vz = q1.z*dx + q2.x*dy + q2.y*dz;
    float maha = dx*vx + dy*vy + dz*vz;      // includes the 0.5
    float w = __expf(q2.z - maha);           // op * exp(-0.5*maha)
    opac += w;

    if (__any(w > 1e-9f)) {
        float4 q3 = R[3], q4 = R[4], q5 = R[5], q6 = R[6];
        float rinv = rsqrtf(d2);
        float x = -dx * rinv, y = -dy * rinv, z = -dz * rinv;
        float xx = x*x, yy = y*y, zz = z*z;
        float xy = x*y, yz = y*z, xz = x*z;

        float res = q3.x;
        res += y * q3.y;
        res += z * q3.z;
        res += x * q3.w;
        res += xy * q4.x;
        res += yz * q4.y;
        res += (3.f*zz - 1.f) * q4.z;
        res += xz * q4.w;
        float xxmyy = xx - yy;
        res += xxmyy * q5.x;
        res += y * (3.f*xx - yy) * q5.y;
        res += (xy * z) * q5.z;
        float f5z1 = 5.f*zz - 1.f;
        res += y * f5z1 * q5.w;
        res += z * (5.f*zz - 3.f) * q6.x;
        res += x * f5z1 * q6.y;
        res += z * xxmyy * q6.z;
        res += x * (xxmyy - 3.f*zz) * q6.w;

        sig += w * fmaxf(res, 0.f);
    }
}

// ---------------------------------------------------------------------------
// N5: balanced eval. Block (ck, pb) evals survivors [nact*ck/32, nact*(ck+1)/32)
// of point-block pb. R10: accumulate DIRECTLY into out[orig] (orig rides in
// P.w) — permute kernel + acc buffer eliminated. Contention identical to acc
// (same 32 adds/address); addressing uncoalesced but out is 256KB L2-resident.
// ---------------------------------------------------------------------------
__global__ __launch_bounds__(BLOCK) void eval_kernel(
    const float4* __restrict__ spts, const float4* __restrict__ gp4,
    const int* __restrict__ actlist, const int* __restrict__ nactg,
    float* __restrict__ out)
{
    __shared__ float4 s_rec[RECCAP * 8];     // 16 KB

    const int tid = threadIdx.x;
    const int ck  = blockIdx.x;
    const int pb  = blockIdx.y;

    const int nact = nactg[pb];
    const int c0 = (nact * ck) / NCHUNK;
    const int c1 = (nact * (ck + 1)) / NCHUNK;
    const int cnt = c1 - c0;
    if (cnt == 0) return;

    float4 P = spts[pb * 256 + tid];         // issue early, overlaps staging
    const int* alist = actlist + pb * N_GAUSS + c0;

    // stage records into LDS: 8 lanes per record read one 128B line;
    // alist[rec] is a broadcast across those 8 lanes (L2-hot).
    for (int idx = tid; idx < cnt * 8; idx += BLOCK) {
        int rec = idx >> 3, q = idx & 7;
        s_rec[idx] = gp4[((size_t)alist[rec] << 3) + q];
    }
    __syncthreads();

    const float px = P.x, py = P.y, pz = P.z;
    float opac = 0.f, sig = 0.f;
    int j = 0;
    for (; j + 4 <= cnt; j += 4) {
        const float4* R0 = &s_rec[(j + 0) * 8];
        const float4* R1 = &s_rec[(j + 1) * 8];
        const float4* R2 = &s_rec[(j + 2) * 8];
        const float4* R3 = &s_rec[(j + 3) * 8];
        float4 a = R0[0], b = R1[0], c = R2[0], d = R3[0];
        float adx = px - a.x, ady = py - a.y, adz = pz - a.z;
        float bdx = px - b.x, bdy = py - b.y, bdz = pz - b.z;
        float cdx = px - c.x, cdy = py - c.y, cdz = pz - c.z;
        float ddx = px - d.x, ddy = py - d.y, ddz = pz - d.z;
        float ad2 = adx*adx + ady*ady + adz*adz;
        float bd2 = bdx*bdx + bdy*bdy + bdz*bdz;
        float cd2 = cdx*cdx + cdy*cdy + cdz*cdz;
        float dd2 = ddx*ddx + ddy*ddy + ddz*ddz;

        if (!__all(ad2 > a.w)) eval_one(R0, adx, ady, adz, ad2, opac, sig);
        if (!__all(bd2 > b.w)) eval_one(R1, bdx, bdy, bdz, bd2, opac, sig);
        if (!__all(cd2 > c.w)) eval_one(R2, cdx, cdy, cdz, cd2, opac, sig);
        if (!__all(dd2 > d.w)) eval_one(R3, ddx, ddy, ddz, dd2, opac, sig);
    }
    for (; j < cnt; ++j) {
        const float4* R0 = &s_rec[j * 8];
        float4 a = R0[0];
        float adx = px - a.x, ady = py - a.y, adz = pz - a.z;
        float ad2 = adx*adx + ady*ady + adz*adz;
        if (!__all(ad2 > a.w)) eval_one(R0, adx, ady, adz, ad2, opac, sig);
    }

    // direct scattered atomics into final output (orig index from P.w)
    const int orig = __float_as_int(P.w);
    atomicAdd(&out[orig], opac);
    atomicAdd(&out[N_PTS + orig], sig);
}

extern "C" void kernel_launch(void* const* d_in, const int* in_sizes, int n_in,
                              void* d_out, int out_size, void* d_ws, size_t ws_size,
                              hipStream_t stream) {
    const float* pts      = (const float*)d_in[0];
    const float* xyz      = (const float*)d_in[3];
    const float* sh_dc    = (const float*)d_in[4];
    const float* sh_rest  = (const float*)d_in[5];
    const float* scaling  = (const float*)d_in[6];
    const float* rotation = (const float*)d_in[7];
    const float* opl      = (const float*)d_in[8];

    float*  out     = (float*)d_out;
    float*  wsf     = (float*)d_ws;
    float*  gp      = wsf + WS_GP;
    int*    ghist   = (int*)(wsf + WS_GHIST);
    int*    cellid  = (int*)(wsf + WS_CELLID);
    float4* spts    = (float4*)(wsf + WS_SPTS);
    int*    hpart   = (int*)(wsf + WS_HPART);
    int*    actlist = (int*)(wsf + WS_ACT);
    int*    nactg   = (int*)(wsf + WS_NACT);

    binprep_kernel<<<dim3(28), dim3(1024), 0, stream>>>(
        pts, xyz, sh_dc, sh_rest, scaling, rotation, opl, gp, cellid, hpart, out);
    scan_kernel<<<dim3(1), dim3(1024), 0, stream>>>(hpart, ghist);
    scatter_kernel<<<dim3(NBLK_PT), dim3(256), 0, stream>>>(pts, cellid, ghist, spts);

    cull_kernel<<<dim3(NBLK_PT), dim3(BLOCK), 0, stream>>>(
        spts, (const float4*)gp, actlist, nactg);
    eval_kernel<<<dim3(NCHUNK, NBLK_PT), dim3(BLOCK), 0, stream>>>(
        spts, (const float4*)gp, actlist, nactg, out);
}

// Round 11
// 118.869 us; speedup vs baseline: 1.7920x; 1.7920x over previous
//
#include <hip/hip_runtime.h>
#include <hip/hip_bf16.h>

// ---- problem constants ----
#define N_GAUSS 4096
#define N_PTS   32768
#define BLOCK   256
#define NCHUNK  32                  // eval chunks per point-block; grid 32 x 128
#define NBLK_PT 128                 // 128 x 256 = 32768 points
#define GSTRIDE 32                  // floats per packed gaussian = 8 x float4
#define NCELL   4096                // 16^3 morton cells
#define NBIN    16                  // parallel bin blocks (R5-proven shape)
#define RECCAP  128                 // max records per eval chunk (= ceil(4096/32))

#define SH_C0  0.28209479177387814f
#define SH_C1  0.4886025119029199f

// Workspace layout (float index):
#define WS_GP     0                          // 4096*32 = 131072 floats
#define WS_GHIST  131072                     // int[4096]  (scan output / scatter cursor)
#define WS_CELLID 135168                     // int[32768]
#define WS_SPTS   167936                     // float4[32768] (16B aligned)
#define WS_ACC    299008                     // float[65536]
#define WS_HPART  364544                     // int[16*4096] partial histograms
#define WS_ACT    430080                     // int[128*4096] survivor lists
#define WS_NACT   954368                     // int[128] survivor counts
// total ~954,496 floats = 3.8 MB

// R10 LESSON (counters: WRITE_SIZE 4MB->65MB, eval 25->117us): scattered
// device-scope float atomics are serviced MEMORY-SIDE on CDNA4 (per-XCD L2s
// non-coherent) — 64 lines/wave instead of 4 coalesced = ~16x atomic traffic.
// Coalesced atomics into sorted-order acc + plain-store permute is mandatory.

__device__ __forceinline__ int cell_of(float x, float y, float z) {
    int cx = min(15, max(0, (int)((x + 3.2f) * 2.5f)));
    int cy = min(15, max(0, (int)((y + 3.2f) * 2.5f)));
    int cz = min(15, max(0, (int)((z + 3.2f) * 2.5f)));
    int ex = (cx & 1) | ((cx & 2) << 2) | ((cx & 4) << 4) | ((cx & 8) << 6);
    int ey = (cy & 1) | ((cy & 2) << 2) | ((cy & 4) << 4) | ((cy & 8) << 6);
    int ez = (cz & 1) | ((cz & 2) << 2) | ((cz & 4) << 4) | ((cz & 8) << 6);
    return ex | (ey << 1) | (ez << 2);
}

// ---------------------------------------------------------------------------
// N1 (28 blocks x 1024): blocks 0..15 bin 2048 pts each (LDS hist -> partial
// dump); blocks 16..19 gaussian prep (float4 record stores); 20..27 zero acc.
// Record: q0=(cx,cy,cz,Tg) q1=(pxx,pxy,pxz,pyy) q2=(pyz,pzz,lnop,0)
//         q3..q6 = SH (constants pre-multiplied), q7 = pad
// ---------------------------------------------------------------------------
__global__ __launch_bounds__(1024) void binprep_kernel(
    const float* __restrict__ pts, const float* __restrict__ xyz,
    const float* __restrict__ sh_dc, const float* __restrict__ sh_rest,
    const float* __restrict__ scaling, const float* __restrict__ rotation,
    const float* __restrict__ opl, float* __restrict__ gp,
    int* __restrict__ cellid, int* __restrict__ hpart, float* __restrict__ acc)
{
    const int t = threadIdx.x, bx = blockIdx.x;

    if (bx >= 20) {
        float4* a4 = (float4*)acc;
        int base = (bx - 20) * 2048 + t;
        a4[base]        = make_float4(0.f, 0.f, 0.f, 0.f);
        a4[base + 1024] = make_float4(0.f, 0.f, 0.f, 0.f);
        return;
    }
    if (bx >= 16) {
        int g = (bx - 16) * 1024 + t;
        float s0 = scaling[3*g+0], s1 = scaling[3*g+1], s2 = scaling[3*g+2];
        float i0 = __expf(-2.0f * s0);
        float i1 = __expf(-2.0f * s1);
        float i2 = __expf(-2.0f * s2);
        float maxs2 = __expf(2.0f * fmaxf(s0, fmaxf(s1, s2)));

        float r = rotation[4*g+0], x = rotation[4*g+1];
        float y = rotation[4*g+2], z = rotation[4*g+3];
        float n = rsqrtf(r*r + x*x + y*y + z*z);
        r *= n; x *= n; y *= n; z *= n;
        float R00 = 1.f - 2.f*(y*y + z*z), R01 = 2.f*(x*y - r*z), R02 = 2.f*(x*z + r*y);
        float R10 = 2.f*(x*y + r*z), R11 = 1.f - 2.f*(x*x + z*z), R12 = 2.f*(y*z - r*x);
        float R20 = 2.f*(x*z - r*y), R21 = 2.f*(y*z + r*x), R22 = 1.f - 2.f*(x*x + y*y);

        float pxx = 0.5f*(R00*R00*i0 + R01*R01*i1 + R02*R02*i2);
        float pxy = 0.5f*(R00*R10*i0 + R01*R11*i1 + R02*R12*i2);
        float pxz = 0.5f*(R00*R20*i0 + R01*R21*i1 + R02*R22*i2);
        float pyy = 0.5f*(R10*R10*i0 + R11*R11*i1 + R12*R12*i2);
        float pyz = 0.5f*(R10*R20*i0 + R11*R21*i1 + R12*R22*i2);
        float pzz = 0.5f*(R20*R20*i0 + R21*R21*i1 + R22*R22*i2);

        float op   = 1.f / (1.f + __expf(-opl[g]));
        float lnop = __logf(op);
        // d2 > Tg => w < e^-16 ~ 1.1e-7; dropped total ~2e-3 << 4.1e-2 threshold
        float Tg   = 2.0f * maxs2 * (lnop + 16.0f);

        const float* sr = sh_rest + (size_t)g * 15;
        float4* G4 = (float4*)(gp + (size_t)g * GSTRIDE);
        G4[0] = make_float4(xyz[3*g+0], xyz[3*g+1], xyz[3*g+2], Tg);
        G4[1] = make_float4(pxx, pxy, pxz, pyy);
        G4[2] = make_float4(pyz, pzz, lnop, 0.f);
        G4[3] = make_float4( SH_C0 * sh_dc[g],
                            -SH_C1 * sr[0],
                             SH_C1 * sr[1],
                            -SH_C1 * sr[2]);
        G4[4] = make_float4( 1.0925484305920792f  * sr[3],
                            -1.0925484305920792f  * sr[4],
                             0.31539156525252005f * sr[5],
                            -1.0925484305920792f  * sr[6]);
        G4[5] = make_float4( 0.5462742152960396f  * sr[7],
                            -0.5900435899266435f  * sr[8],
                             2.890611442640554f   * sr[9],
                            -0.4570457994644658f  * sr[10]);
        G4[6] = make_float4( 0.3731763325901154f  * sr[11],
                            -0.4570457994644658f  * sr[12],
                             1.445305721320277f   * sr[13],
                            -0.5900435899266435f  * sr[14]);
        G4[7] = make_float4(0.f, 0.f, 0.f, 0.f);
        return;
    }

    // ---- bin blocks 0..15: 2048 points each ----
    __shared__ int s_hist[NCELL];
    #pragma unroll
    for (int i = 0; i < 4; ++i) s_hist[t + i * 1024] = 0;
    __syncthreads();
    #pragma unroll
    for (int k = 0; k < 2; ++k) {
        int p = bx * 2048 + k * 1024 + t;
        float x = pts[3*p+0], y = pts[3*p+1], z = pts[3*p+2];
        int cell = cell_of(x, y, z);
        cellid[p] = cell;
        atomicAdd(&s_hist[cell], 1);
    }
    __syncthreads();
    #pragma unroll
    for (int i = 0; i < 4; ++i) {
        int c = t + i * 1024;
        hpart[bx * NCELL + c] = s_hist[c];
    }
}

// ---------------------------------------------------------------------------
// N2: one block sums 16 partial hists (int4 loads) + exclusive scan -> ghist.
// ---------------------------------------------------------------------------
__global__ __launch_bounds__(1024) void scan_kernel(
    const int* __restrict__ hpart, int* __restrict__ ghist)
{
    __shared__ int s_wsum[16];
    const int t = threadIdx.x;
    const int lane = t & 63, wv = t >> 6;
    const int b = t * 4;

    int4 c = make_int4(0, 0, 0, 0);
    #pragma unroll
    for (int k = 0; k < NBIN; ++k) {
        int4 h = *(const int4*)(hpart + k * NCELL + b);
        c.x += h.x; c.y += h.y; c.z += h.z; c.w += h.w;
    }
    int s = c.x + c.y + c.z + c.w;

    // inclusive scan within wave (64 lanes)
    int incl = s;
    #pragma unroll
    for (int off = 1; off < 64; off <<= 1) {
        int v = __shfl_up(incl, off);
        if (lane >= off) incl += v;
    }
    if (lane == 63) s_wsum[wv] = incl;
    __syncthreads();
    if (wv == 0) {
        int ws = (lane < 16) ? s_wsum[lane] : 0;
        int wincl = ws;
        #pragma unroll
        for (int off = 1; off < 16; off <<= 1) {
            int v = __shfl_up(wincl, off);
            if (lane >= off) wincl += v;
        }
        if (lane < 16) s_wsum[lane] = wincl - ws;   // exclusive wave offset
    }
    __syncthreads();

    int excl = s_wsum[wv] + (incl - s);
    ghist[b]   = excl;
    ghist[b+1] = excl + c.x;
    ghist[b+2] = excl + c.x + c.y;
    ghist[b+3] = excl + c.x + c.y + c.z;
}

// ---------------------------------------------------------------------------
// N3: scatter points into sorted float4 (xyz + bitcast orig index).
// ---------------------------------------------------------------------------
__global__ __launch_bounds__(256) void scatter_kernel(
    const float* __restrict__ pts, const int* __restrict__ cellid,
    int* __restrict__ ghist, float4* __restrict__ spts)
{
    int p = blockIdx.x * 256 + threadIdx.x;
    float x = pts[3*p+0], y = pts[3*p+1], z = pts[3*p+2];
    int pos = atomicAdd(&ghist[cellid[p]], 1);
    spts[pos] = make_float4(x, y, z, __int_as_float(p));
}

// ---------------------------------------------------------------------------
// N4: cull. One block per point-block: AABB once, test all 4096 gaussians,
// emit compacted survivor list + count. (Produced ONCE per pb — R7 lesson:
// never recompute this in the 32x-multiplicity consumer.)
// ---------------------------------------------------------------------------
__global__ __launch_bounds__(BLOCK) void cull_kernel(
    const float4* __restrict__ spts, const float4* __restrict__ gp4,
    int* __restrict__ actlist, int* __restrict__ nactg)
{
    __shared__ float s_min[4][3], s_max[4][3];
    __shared__ int s_n;
    __shared__ int s_list[N_GAUSS];          // 16 KB

    const int tid = threadIdx.x;
    const int pb  = blockIdx.x;
    float4 P = spts[pb * 256 + tid];
    const float px = P.x, py = P.y, pz = P.z;

    // block AABB
    float mnx = px, mxx = px, mny = py, mxy = py, mnz = pz, mxz = pz;
    #pragma unroll
    for (int off = 32; off >= 1; off >>= 1) {
        mnx = fminf(mnx, __shfl_xor(mnx, off));
        mxx = fmaxf(mxx, __shfl_xor(mxx, off));
        mny = fminf(mny, __shfl_xor(mny, off));
        mxy = fmaxf(mxy, __shfl_xor(mxy, off));
        mnz = fminf(mnz, __shfl_xor(mnz, off));
        mxz = fmaxf(mxz, __shfl_xor(mxz, off));
    }
    const int wave = tid >> 6;
    if ((tid & 63) == 0) {
        s_min[wave][0] = mnx; s_min[wave][1] = mny; s_min[wave][2] = mnz;
        s_max[wave][0] = mxx; s_max[wave][1] = mxy; s_max[wave][2] = mxz;
    }
    if (tid == 0) s_n = 0;
    __syncthreads();
    const float bmnx = fminf(fminf(s_min[0][0], s_min[1][0]), fminf(s_min[2][0], s_min[3][0]));
    const float bmny = fminf(fminf(s_min[0][1], s_min[1][1]), fminf(s_min[2][1], s_min[3][1]));
    const float bmnz = fminf(fminf(s_min[0][2], s_min[1][2]), fminf(s_min[2][2], s_min[3][2]));
    const float bmxx = fmaxf(fmaxf(s_max[0][0], s_max[1][0]), fmaxf(s_max[2][0], s_max[3][0]));
    const float bmxy = fmaxf(fmaxf(s_max[0][1], s_max[1][1]), fmaxf(s_max[2][1], s_max[3][1]));
    const float bmxz = fmaxf(fmaxf(s_max[0][2], s_max[1][2]), fmaxf(s_max[2][2], s_max[3][2]));

    for (int r = 0; r < N_GAUSS / BLOCK; ++r) {
        const int gg = r * BLOCK + tid;
        float4 c = gp4[(size_t)gg << 3];
        float ddx = fmaxf(0.f, fmaxf(bmnx - c.x, c.x - bmxx));
        float ddy = fmaxf(0.f, fmaxf(bmny - c.y, c.y - bmxy));
        float ddz = fmaxf(0.f, fmaxf(bmnz - c.z, c.z - bmxz));
        float dd2 = ddx*ddx + ddy*ddy + ddz*ddz;
        if (dd2 <= c.w) {
            int slot = atomicAdd(&s_n, 1);
            s_list[slot] = gg;
        }
    }
    __syncthreads();
    const int n = s_n;
    for (int i = tid; i < n; i += BLOCK) actlist[pb * N_GAUSS + i] = s_list[i];
    if (tid == 0) nactg[pb] = n;
}

// ---------------------------------------------------------------------------
// Eval body for one surviving LDS record (R16-proven math).
// ---------------------------------------------------------------------------
__device__ __forceinline__ void eval_one(
    const float4* R, float dx, float dy, float dz, float d2,
    float& opac, float& sig)
{
    float4 q1 = R[1], q2 = R[2];
    float vx = q1.x*dx + q1.y*dy + q1.z*dz;
    float vy = q1.y*dx + q1.w*dy + q2.x*dz;
    float vz = q1.z*dx + q2.x*dy + q2.y*dz;
    float maha = dx*vx + dy*vy + dz*vz;      // includes the 0.5
    float w = __expf(q2.z - maha);           // op * exp(-0.5*maha)
    opac += w;

    if (__any(w > 1e-9f)) {
        float4 q3 = R[3], q4 = R[4], q5 = R[5], q6 = R[6];
        float rinv = rsqrtf(d2);
        float x = -dx * rinv, y = -dy * rinv, z = -dz * rinv;
        float xx = x*x, yy = y*y, zz = z*z;
        float xy = x*y, yz = y*z, xz = x*z;

        float res = q3.x;
        res += y * q3.y;
        res += z * q3.z;
        res += x * q3.w;
        res += xy * q4.x;
        res += yz * q4.y;
        res += (3.f*zz - 1.f) * q4.z;
        res += xz * q4.w;
        float xxmyy = xx - yy;
        res += xxmyy * q5.x;
        res += y * (3.f*xx - yy) * q5.y;
        res += (xy * z) * q5.z;
        float f5z1 = 5.f*zz - 1.f;
        res += y * f5z1 * q5.w;
        res += z * (5.f*zz - 3.f) * q6.x;
        res += x * f5z1 * q6.y;
        res += z * xxmyy * q6.z;
        res += x * (xxmyy - 3.f*zz) * q6.w;

        sig += w * fmaxf(res, 0.f);
    }
}

// ---------------------------------------------------------------------------
// N5: balanced eval. Block (ck, pb) evals survivors [nact*ck/32, nact*(ck+1)/32)
// of point-block pb. Coalesced atomics into sorted-order acc (R10 lesson).
// ---------------------------------------------------------------------------
__global__ __launch_bounds__(BLOCK) void eval_kernel(
    const float4* __restrict__ spts, const float4* __restrict__ gp4,
    const int* __restrict__ actlist, const int* __restrict__ nactg,
    float* __restrict__ acc)
{
    __shared__ float4 s_rec[RECCAP * 8];     // 16 KB

    const int tid = threadIdx.x;
    const int ck  = blockIdx.x;
    const int pb  = blockIdx.y;

    const int nact = nactg[pb];
    const int c0 = (nact * ck) / NCHUNK;
    const int c1 = (nact * (ck + 1)) / NCHUNK;
    const int cnt = c1 - c0;
    if (cnt == 0) return;

    float4 P = spts[pb * 256 + tid];         // issue early, overlaps staging
    const int* alist = actlist + pb * N_GAUSS + c0;

    // stage records into LDS: 8 lanes per record read one 128B line;
    // alist[rec] is a broadcast across those 8 lanes (L2-hot).
    for (int idx = tid; idx < cnt * 8; idx += BLOCK) {
        int rec = idx >> 3, q = idx & 7;
        s_rec[idx] = gp4[((size_t)alist[rec] << 3) + q];
    }
    __syncthreads();

    const float px = P.x, py = P.y, pz = P.z;
    float opac = 0.f, sig = 0.f;
    int j = 0;
    for (; j + 4 <= cnt; j += 4) {
        const float4* R0 = &s_rec[(j + 0) * 8];
        const float4* R1 = &s_rec[(j + 1) * 8];
        const float4* R2 = &s_rec[(j + 2) * 8];
        const float4* R3 = &s_rec[(j + 3) * 8];
        float4 a = R0[0], b = R1[0], c = R2[0], d = R3[0];
        float adx = px - a.x, ady = py - a.y, adz = pz - a.z;
        float bdx = px - b.x, bdy = py - b.y, bdz = pz - b.z;
        float cdx = px - c.x, cdy = py - c.y, cdz = pz - c.z;
        float ddx = px - d.x, ddy = py - d.y, ddz = pz - d.z;
        float ad2 = adx*adx + ady*ady + adz*adz;
        float bd2 = bdx*bdx + bdy*bdy + bdz*bdz;
        float cd2 = cdx*cdx + cdy*cdy + cdz*cdz;
        float dd2 = ddx*ddx + ddy*ddy + ddz*ddz;

        if (!__all(ad2 > a.w)) eval_one(R0, adx, ady, adz, ad2, opac, sig);
        if (!__all(bd2 > b.w)) eval_one(R1, bdx, bdy, bdz, bd2, opac, sig);
        if (!__all(cd2 > c.w)) eval_one(R2, cdx, cdy, cdz, cd2, opac, sig);
        if (!__all(dd2 > d.w)) eval_one(R3, ddx, ddy, ddz, dd2, opac, sig);
    }
    for (; j < cnt; ++j) {
        const float4* R0 = &s_rec[j * 8];
        float4 a = R0[0];
        float adx = px - a.x, ady = py - a.y, adz = pz - a.z;
        float ad2 = adx*adx + ady*ady + adz*adz;
        if (!__all(ad2 > a.w)) eval_one(R0, adx, ady, adz, ad2, opac, sig);
    }

    // coalesced atomics: wave hits 64 consecutive floats
    const int pos = pb * 256 + tid;
    atomicAdd(&acc[pos], opac);
    atomicAdd(&acc[N_PTS + pos], sig);
}

// ---------------------------------------------------------------------------
// N6: permute acc (sorted index) -> out (original index), plain stores.
// ---------------------------------------------------------------------------
__global__ __launch_bounds__(256) void permute_kernel(
    const float* __restrict__ acc, const float4* __restrict__ spts,
    float* __restrict__ out)
{
    int p = blockIdx.x * 256 + threadIdx.x;
    int orig = __float_as_int(spts[p].w);
    out[orig] = acc[p];
    out[N_PTS + orig] = acc[N_PTS + p];
}

extern "C" void kernel_launch(void* const* d_in, const int* in_sizes, int n_in,
                              void* d_out, int out_size, void* d_ws, size_t ws_size,
                              hipStream_t stream) {
    const float* pts      = (const float*)d_in[0];
    const float* xyz      = (const float*)d_in[3];
    const float* sh_dc    = (const float*)d_in[4];
    const float* sh_rest  = (const float*)d_in[5];
    const float* scaling  = (const float*)d_in[6];
    const float* rotation = (const float*)d_in[7];
    const float* opl      = (const float*)d_in[8];

    float*  out     = (float*)d_out;
    float*  wsf     = (float*)d_ws;
    float*  gp      = wsf + WS_GP;
    int*    ghist   = (int*)(wsf + WS_GHIST);
    int*    cellid  = (int*)(wsf + WS_CELLID);
    float4* spts    = (float4*)(wsf + WS_SPTS);
    float*  acc     = wsf + WS_ACC;
    int*    hpart   = (int*)(wsf + WS_HPART);
    int*    actlist = (int*)(wsf + WS_ACT);
    int*    nactg   = (int*)(wsf + WS_NACT);

    binprep_kernel<<<dim3(28), dim3(1024), 0, stream>>>(
        pts, xyz, sh_dc, sh_rest, scaling, rotation, opl, gp, cellid, hpart, acc);
    scan_kernel<<<dim3(1), dim3(1024), 0, stream>>>(hpart, ghist);
    scatter_kernel<<<dim3(NBLK_PT), dim3(256), 0, stream>>>(pts, cellid, ghist, spts);

    cull_kernel<<<dim3(NBLK_PT), dim3(BLOCK), 0, stream>>>(
        spts, (const float4*)gp, actlist, nactg);
    eval_kernel<<<dim3(NCHUNK, NBLK_PT), dim3(BLOCK), 0, stream>>>(
        spts, (const float4*)gp, actlist, nactg, acc);
    permute_kernel<<<dim3(NBLK_PT), dim3(256), 0, stream>>>(acc, spts, out);
}